// Round 10
// baseline (47.141 us; speedup 1.0000x reference)
//
#include <hip/hip_runtime.h>

typedef __bf16 bf16x8 __attribute__((ext_vector_type(8)));
typedef float  f32x4  __attribute__((ext_vector_type(4)));

__device__ __forceinline__ unsigned short f2bf(float f) {
    unsigned int u = __float_as_uint(f);
    u += 0x7FFF + ((u >> 16) & 1);          // RNE
    return (unsigned short)(u >> 16);
}
__device__ __forceinline__ unsigned int pk2bf(float a, float b) {
    return (unsigned int)f2bf(a) | ((unsigned int)f2bf(b) << 16);
}

#define GLD_LDS16(gptr, lptr) \
    __builtin_amdgcn_global_load_lds((const __attribute__((address_space(1))) void*)(gptr), \
                                     (__attribute__((address_space(3))) void*)(lptr), 16, 0, 0)

// ===== K1: blocks [0,64)  : small GEMM wcT=(wv@wp)^T, fp32 weights inline-converted;
//           blocks [64,320): partial sums of x (32-row chunks) -> part
__global__ __launch_bounds__(256) void k1_gemm_partial(
    const float* __restrict__ x, const float* __restrict__ w_attn,
    const float* __restrict__ w_proj,
    unsigned short* __restrict__ wcT, float* __restrict__ part)
{
    __shared__ __align__(16) unsigned short As[2][64 * 64];
    __shared__ __align__(16) unsigned short Bs[2][64 * 64];
    const int bid = blockIdx.x, tid = threadIdx.x;

    if (bid < 64) {
        const int bm = (bid >> 3) * 64, bn = (bid & 7) * 64;
        const int lane = tid & 63, w = tid >> 6, wm = w >> 1, wn = w & 1;
        const int arow = lane & 15, kg = lane >> 4;
        const int ir = tid >> 2;          // 0..63
        const int q  = tid & 3;           // 16-col group

        int offA[2][2], offB[2][2];
        #pragma unroll
        for (int f = 0; f < 2; ++f)
            #pragma unroll
            for (int kk = 0; kk < 2; ++kk) {
                offA[f][kk] = (wm * 32 + f * 16 + arow) * 128 + (((kk * 4 + kg) ^ (arow & 7)) << 4);
                offB[f][kk] = (wn * 32 + f * 16 + arow) * 128 + (((kk * 4 + kg) ^ (arow & 7)) << 4);
            }

        f32x4 acc[2][2] = {};
        float4 aR[4], bR[4];

        auto load_regs = [&](int kt) {
            const float* ap = w_attn + (size_t)(bm + ir) * 1536 + 1024 + kt * 64 + q * 16;
            #pragma unroll
            for (int u = 0; u < 4; ++u) aR[u] = *(const float4*)(ap + u * 4);
            const float* bp = w_proj + (size_t)(kt * 64 + ir) * 512 + bn + q * 16;
            #pragma unroll
            for (int u = 0; u < 4; ++u) bR[u] = *(const float4*)(bp + u * 4);
        };
        auto cvt_write = [&](int buf) {
            uint4 lo, hi;
            lo.x = pk2bf(aR[0].x, aR[0].y); lo.y = pk2bf(aR[0].z, aR[0].w);
            lo.z = pk2bf(aR[1].x, aR[1].y); lo.w = pk2bf(aR[1].z, aR[1].w);
            hi.x = pk2bf(aR[2].x, aR[2].y); hi.y = pk2bf(aR[2].z, aR[2].w);
            hi.z = pk2bf(aR[3].x, aR[3].y); hi.w = pk2bf(aR[3].z, aR[3].w);
            char* a = (char*)As[buf] + ir * 128;
            *(uint4*)(a + (((q * 2    ) ^ (ir & 7)) << 4)) = lo;
            *(uint4*)(a + (((q * 2 + 1) ^ (ir & 7)) << 4)) = hi;
            // B transpose: element (k=ir, n-local jl) -> Bs[jl][ir], q-rotated s-order
            char* bmem = (char*)Bs[buf];
            const float* br = (const float*)bR;
            #pragma unroll
            for (int s = 0; s < 16; ++s) {
                const int js = (s + 2 * q) & 15;           // spread 4 q-groups across banks
                const int jl = q * 16 + js;
                *(unsigned short*)(bmem + jl * 128 + (((ir >> 3) ^ (jl & 7)) << 4) + (ir & 7) * 2)
                    = f2bf(br[js]);
            }
        };

        load_regs(0); cvt_write(0); __syncthreads();
        for (int kt = 0; kt < 8; ++kt) {
            const int buf = kt & 1;
            if (kt < 7) load_regs(kt + 1);
            const char* la = (const char*)As[buf];
            const char* lb = (const char*)Bs[buf];
            #pragma unroll
            for (int kk = 0; kk < 2; ++kk) {
                bf16x8 a0 = *(const bf16x8*)(la + offA[0][kk]);
                bf16x8 a1 = *(const bf16x8*)(la + offA[1][kk]);
                bf16x8 b0 = *(const bf16x8*)(lb + offB[0][kk]);
                bf16x8 b1 = *(const bf16x8*)(lb + offB[1][kk]);
                acc[0][0] = __builtin_amdgcn_mfma_f32_16x16x32_bf16(a0, b0, acc[0][0], 0, 0, 0);
                acc[0][1] = __builtin_amdgcn_mfma_f32_16x16x32_bf16(a0, b1, acc[0][1], 0, 0, 0);
                acc[1][0] = __builtin_amdgcn_mfma_f32_16x16x32_bf16(a1, b0, acc[1][0], 0, 0, 0);
                acc[1][1] = __builtin_amdgcn_mfma_f32_16x16x32_bf16(a1, b1, acc[1][1], 0, 0, 0);
            }
            __syncthreads();
            if (kt < 7) { cvt_write(buf ^ 1); __syncthreads(); }
        }
        #pragma unroll
        for (int fm = 0; fm < 2; ++fm)
            #pragma unroll
            for (int fn = 0; fn < 2; ++fn) {
                const int row0 = bm + wm * 32 + fm * 16 + kg * 4;
                const int col  = bn + wn * 32 + fn * 16 + arow;
                ushort4 pk;
                pk.x = f2bf(acc[fm][fn][0]);
                pk.y = f2bf(acc[fm][fn][1]);
                pk.z = f2bf(acc[fm][fn][2]);
                pk.w = f2bf(acc[fm][fn][3]);
                *(ushort4*)(&wcT[(size_t)col * 512 + row0]) = pk;   // C^T
            }
    } else {
        const int bx = bid - 64;              // 0..255
        const int b  = bx >> 7;
        const int ch = (bx >> 1) & 63;
        const int j  = (bx & 1) * 256 + tid;
        const float* p = x + ((size_t)b * 2048 + ch * 32) * 512 + j;
        float s = 0.f;
        #pragma unroll 8
        for (int t = 0; t < 32; ++t) s += p[(size_t)t * 512];
        part[((size_t)b * 64 + ch) * 512 + j] = s;
    }
}

// ===== K2: fused finalize + big GEMM. 128 blocks = 64 m-tiles x 2 n-halves.
// Each block: build 64x512 bf16 A-tile (prefix + cumsum) in LDS once, then
// 4 n-tiles of 64x64 MFMA with double-buffered B staging.
__global__ __launch_bounds__(256) void k2_fused(
    const float* __restrict__ x,
    const unsigned short* __restrict__ wcT,
    const float* __restrict__ part,
    float* __restrict__ y)
{
    __shared__ __align__(16) unsigned short Atile[64 * 512];   // 64 KB
    __shared__ __align__(16) unsigned short Bs[2][64 * 64];    // 16 KB

    const int b0   = blockIdx.x;             // 0..127
    const int xcd  = b0 & 7;
    const int slot = b0 >> 3;                // 0..15
    const int mt   = xcd * 8 + (slot >> 1);  // both nh of an mt land on one XCD
    const int nh   = slot & 1;

    const int tid  = threadIdx.x;
    const int lane = tid & 63, w = tid >> 6, wm = w >> 1, wn = w & 1;
    const int arow = lane & 15, kg = lane >> 4;

    // --- B staging (same proven path as before), issue first tile pre-prologue
    const int srow   = w * 16 + (lane >> 3);
    const int schunk = (lane & 7) ^ (lane >> 3);
    const unsigned short* gBbase = wcT + (size_t)(nh * 256 + srow) * 512 + schunk * 8;
    auto stageB = [&](int buf, int nt, int kt) {
        const unsigned short* g = gBbase + (size_t)(nt * 64) * 512 + kt * 64;
        GLD_LDS16(g,                   Bs[buf] + (w * 16 + 0) * 64);
        GLD_LDS16(g + (size_t)8 * 512, Bs[buf] + (w * 16 + 8) * 64);
    };
    stageB(0, 0, 0);

    // --- prologue: prefix over part (masked fixed-trip, pipelined) + 64-row cumsum
    const int bb = mt >> 5, c2 = (mt & 31) * 2;
    const int k0 = tid * 2;
    float rx = 0.f, ry = 0.f;
    #pragma unroll 9
    for (int cc = 0; cc < 63; ++cc) {
        float2 v = *(const float2*)(part + ((size_t)bb * 64 + cc) * 512 + k0);
        rx += (cc < c2) ? v.x : 0.f;
        ry += (cc < c2) ? v.y : 0.f;
    }
    {
        const float* xp = x + (size_t)mt * 64 * 512 + k0;
        const int cbase = tid >> 2;           // true 16B chunk 0..63
        const int sub   = (tid & 3) * 4;
        #pragma unroll 8
        for (int t = 0; t < 64; ++t) {
            float2 v = *(const float2*)(xp + (size_t)t * 512);
            rx += v.x; ry += v.y;
            const float inv = 1.0f / (float)((mt & 31) * 64 + t + 1);
            *(unsigned int*)((char*)Atile + t * 1024 + ((cbase ^ (t & 7)) << 4) + sub)
                = pk2bf(rx * inv, ry * inv);
        }
    }
    asm volatile("s_waitcnt vmcnt(0) lgkmcnt(0)" ::: "memory");
    __builtin_amdgcn_s_barrier();

    int offB[2][2];
    #pragma unroll
    for (int f = 0; f < 2; ++f)
        #pragma unroll
        for (int kk = 0; kk < 2; ++kk)
            offB[f][kk] = (wn * 32 + f * 16 + arow) * 128 + (((kk * 4 + kg) ^ (arow & 7)) << 4);
    const int ar0 = (wm * 32 +  0 + arow) * 1024;   // A row byte offsets (row stride 1024B)
    const int ar1 = (wm * 32 + 16 + arow) * 1024;
    const int axor0 = ((0 * 4 + kg) ^ (arow & 7)) << 4;
    const int axor1 = ((1 * 4 + kg) ^ (arow & 7)) << 4;

    f32x4 acc[2][2] = {};
    #pragma unroll
    for (int s = 0; s < 32; ++s) {
        const int nt = s >> 3, kt = s & 7, buf = s & 1;
        if (s < 31) stageB(buf ^ 1, (s + 1) >> 3, (s + 1) & 7);
        const char* la = (const char*)Atile + (kt * 8 << 4);     // + kt chunk-group
        const char* lb = (const char*)Bs[buf];
        {
            bf16x8 a0 = *(const bf16x8*)(la + ar0 + axor0);
            bf16x8 a1 = *(const bf16x8*)(la + ar1 + axor0);
            bf16x8 b0 = *(const bf16x8*)(lb + offB[0][0]);
            bf16x8 b1 = *(const bf16x8*)(lb + offB[1][0]);
            acc[0][0] = __builtin_amdgcn_mfma_f32_16x16x32_bf16(a0, b0, acc[0][0], 0, 0, 0);
            acc[0][1] = __builtin_amdgcn_mfma_f32_16x16x32_bf16(a0, b1, acc[0][1], 0, 0, 0);
            acc[1][0] = __builtin_amdgcn_mfma_f32_16x16x32_bf16(a1, b0, acc[1][0], 0, 0, 0);
            acc[1][1] = __builtin_amdgcn_mfma_f32_16x16x32_bf16(a1, b1, acc[1][1], 0, 0, 0);
        }
        {
            bf16x8 a0 = *(const bf16x8*)(la + ar0 + axor1);
            bf16x8 a1 = *(const bf16x8*)(la + ar1 + axor1);
            bf16x8 b0 = *(const bf16x8*)(lb + offB[0][1]);
            bf16x8 b1 = *(const bf16x8*)(lb + offB[1][1]);
            acc[0][0] = __builtin_amdgcn_mfma_f32_16x16x32_bf16(a0, b0, acc[0][0], 0, 0, 0);
            acc[0][1] = __builtin_amdgcn_mfma_f32_16x16x32_bf16(a0, b1, acc[0][1], 0, 0, 0);
            acc[1][0] = __builtin_amdgcn_mfma_f32_16x16x32_bf16(a1, b0, acc[1][0], 0, 0, 0);
            acc[1][1] = __builtin_amdgcn_mfma_f32_16x16x32_bf16(a1, b1, acc[1][1], 0, 0, 0);
        }
        asm volatile("s_waitcnt vmcnt(0)" ::: "memory");
        __builtin_amdgcn_s_barrier();
        if (kt == 7) {
            #pragma unroll
            for (int fm = 0; fm < 2; ++fm)
                #pragma unroll
                for (int fn = 0; fn < 2; ++fn) {
                    const int row0 = mt * 64 + wm * 32 + fm * 16 + kg * 4;
                    const int col  = nh * 256 + nt * 64 + wn * 32 + fn * 16 + arow;
                    #pragma unroll
                    for (int r = 0; r < 4; ++r)
                        y[(size_t)(row0 + r) * 512 + col] = acc[fm][fn][r];
                    acc[fm][fn] = (f32x4){0.f, 0.f, 0.f, 0.f};
                }
        }
    }
}

extern "C" void kernel_launch(void* const* d_in, const int* in_sizes, int n_in,
                              void* d_out, int out_size, void* d_ws, size_t ws_size,
                              hipStream_t stream)
{
    const float* x      = (const float*)d_in[0];   // (2,2048,512) fp32, 8.4 MB
    const float* w_attn = (const float*)d_in[1];   // (512,1536); V = cols [1024,1536)
    const float* w_proj = (const float*)d_in[2];   // (512,512)
    float* y = (float*)d_out;

    unsigned short* wcT = (unsigned short*)d_ws;    // [512][512] bf16 ((wv@wp)^T)
    float* part = (float*)(wcT + 512 * 512);        // [2][64][512] f32 (32-row chunk sums)

    k1_gemm_partial<<<320, 256, 0, stream>>>(x, w_attn, w_proj, wcT, part);
    k2_fused<<<128, 256, 0, stream>>>(x, wcT, part, y);
}